// Round 1
// 2004.292 us; speedup vs baseline: 1.0133x; 1.0133x over previous
//
#include <hip/hip_runtime.h>
#include <hip/hip_bf16.h>
#include <math.h>

typedef __attribute__((ext_vector_type(8))) short short8;
typedef __attribute__((ext_vector_type(4))) float f32x4;

__device__ __forceinline__ float bf2f(unsigned short u) {
  union { unsigned int i; float f; } v; v.i = ((unsigned int)u) << 16; return v.f;
}
__device__ __forceinline__ unsigned short f2bf(float f) {
  union { float f; unsigned int i; } v; v.f = f;
  unsigned int r = v.i + 0x7fffu + ((v.i >> 16) & 1u);
  return (unsigned short)(r >> 16);
}
// convert 8 consecutive fp32 (two aligned float4) -> 8 bf16 (uint4)
__device__ __forceinline__ uint4 cvt8(const float* __restrict__ src, float scale) {
  float4 a = *(const float4*)src;
  float4 b = *(const float4*)(src + 4);
  uint4 o; unsigned short* op = (unsigned short*)&o;
  op[0] = f2bf(a.x * scale); op[1] = f2bf(a.y * scale);
  op[2] = f2bf(a.z * scale); op[3] = f2bf(a.w * scale);
  op[4] = f2bf(b.x * scale); op[5] = f2bf(b.y * scale);
  op[6] = f2bf(b.z * scale); op[7] = f2bf(b.w * scale);
  return o;
}
// async global->LDS, 16 bytes per lane. LDS dest = wave-uniform base + lane*16.
__device__ __forceinline__ void glds16(const unsigned short* g, unsigned short* s) {
  __builtin_amdgcn_global_load_lds(
      (const __attribute__((address_space(1))) unsigned int*)g,
      (__attribute__((address_space(3))) unsigned int*)s, 16, 0, 0);
}

// ---------------- embedding: h = bf16(word_emb[ids] + pos_emb[s]) ----------
__global__ void embed_k(const int* __restrict__ ids, const float* __restrict__ we,
                        const float* __restrict__ pe, unsigned short* __restrict__ h) {
  int t = blockIdx.x * 256 + threadIdx.x;           // 1M threads, 8 elems each
  int c8 = (t & 127) * 8, row = t >> 7;
  int s = row & 2047;
  int id = ids[row];
  const float* ap = we + (size_t)id * 1024 + c8;
  const float* bp = pe + (size_t)s * 1024 + c8;
  float4 a0 = *(const float4*)ap, a1 = *(const float4*)(ap + 4);
  float4 b0 = *(const float4*)bp, b1 = *(const float4*)(bp + 4);
  uint4 o; unsigned short* op = (unsigned short*)&o;
  op[0] = f2bf(a0.x + b0.x); op[1] = f2bf(a0.y + b0.y);
  op[2] = f2bf(a0.z + b0.z); op[3] = f2bf(a0.w + b0.w);
  op[4] = f2bf(a1.x + b1.x); op[5] = f2bf(a1.y + b1.y);
  op[6] = f2bf(a1.z + b1.z); op[7] = f2bf(a1.w + b1.w);
  *(uint4*)(h + (size_t)row * 1024 + c8) = o;
}

// ---------------- lambda / gamma / lambda^64 precompute (all layers) -------
__global__ void prep_lam_k(const float* __restrict__ nu_log,
                           const float* __restrict__ theta_log,
                           float* __restrict__ lamP) {
  int t = blockIdx.x * 256 + threadIdx.x;  // 4096 = L*H
  float nu = nu_log[t], th = theta_log[t];
  float mag = expf(-expf(nu));
  float eth = expf(th);
  float lr = mag * cosf(eth), li = mag * sinf(eth);
  float g2 = 1.0f - mag * mag; if (g2 < 0.f) g2 = 0.f;
  float pr = 1.f, pi = 0.f;
#pragma unroll 1
  for (int i = 0; i < 64; ++i) { float nr = pr * lr - pi * li; pi = pr * li + pi * lr; pr = nr; }
  lamP[t] = lr;                     // plane 0: lam_re
  lamP[4096 + t] = li;              // plane 1: lam_im
  lamP[2 * 4096 + t] = sqrtf(g2);   // plane 2: gamma
  lamP[3 * 4096 + t] = pr;          // plane 3: lam^64 re
  lamP[4 * 4096 + t] = pi;          // plane 4: lam^64 im
}

// -------- per-layer weight repack (fp32->bf16): Bw=[B_re*g;B_im*g], Cw=[C_re|-C_im]
__global__ void prep_w_k(const float* __restrict__ Bre, const float* __restrict__ Bim,
                         const float* __restrict__ Cre, const float* __restrict__ Cim,
                         const float* __restrict__ gamma, unsigned short* __restrict__ Bw,
                         unsigned short* __restrict__ Cw) {
  int t = blockIdx.x * 256 + threadIdx.x;  // 524288
  if (t < 262144) {
    int n = t >> 7, h8 = (t & 127) * 8;
    int u = n & 1023;
    const float* src = (n < 1024 ? Bre : Bim) + (size_t)u * 1024 + h8;
    *(uint4*)(Bw + (size_t)n * 1024 + h8) = cvt8(src, gamma[u]);
  } else {
    int t2 = t - 262144;
    int hrow = t2 >> 8, u8 = (t2 & 255) * 8;
    uint4 o;
    if (u8 < 1024) o = cvt8(Cre + (size_t)hrow * 1024 + u8, 1.0f);
    else           o = cvt8(Cim + (size_t)hrow * 1024 + (u8 - 1024), -1.0f);
    *(uint4*)(Cw + (size_t)hrow * 2048 + u8) = o;
  }
}

// -------- per-chunk FFN weight convert: w1c[1024,1024], w2c[1024,1024] -----
// 262144 threads total: 131072 for w1c (1M elems), 131072 for w2c (1M elems).
__global__ void prep_ffn_k(const float* __restrict__ w1l, const float* __restrict__ w2l,
                           unsigned short* __restrict__ w1c, unsigned short* __restrict__ w2c,
                           int c) {
  int t = blockIdx.x * 256 + threadIdx.x;  // 262144
  if (t < 131072) {
    // w1 chunk: rows [c*1024, (c+1)*1024) of [4096,1024] -> contiguous 1M elems
    size_t off = (size_t)t * 8;
    *(uint4*)(w1c + off) = cvt8(w1l + (size_t)c * 1024 * 1024 + off, 1.0f);
  } else {
    int t2 = t - 131072;                    // [0, 131072)
    int n = t2 >> 7, k8 = (t2 & 127) * 8;   // n in [0,1024), k8 in [0,1024)
    *(uint4*)(w2c + (size_t)n * 1024 + k8) =
        cvt8(w2l + (size_t)n * 4096 + (size_t)c * 1024 + k8, 1.0f);
  }
}

// ---------------- NT bf16 GEMM: C = A[M,K] * B[N,K]^T ----------------------
// m97 structure: global_load_lds width=16 direct staging, 128x128 tile, BK=32.
// EPI: 0 = bf16 store; 2 = bf16 store, +bias +gelu(exact);
//      3 = fp32 store, +bias (accumulator init); 4 = fp32 +=
template <int EPI>
__global__ __launch_bounds__(256, 2) void gemm_nt(
    const unsigned short* __restrict__ A, const unsigned short* __restrict__ Bm,
    void* __restrict__ Cout, const float* __restrict__ bias, int M, int N, int K) {
  __shared__ unsigned short As[128 * 32];
  __shared__ unsigned short Bs[128 * 32];
  const int tid = threadIdx.x;
  const int lane = tid & 63;
  const int wave = tid >> 6;
  const int quad = lane >> 4, r = lane & 15;
  const int wm = (wave >> 1) * 64, wn = (wave & 1) * 64;
  const size_t row0 = (size_t)blockIdx.x * 128;
  const size_t col0 = (size_t)blockIdx.y * 128;
  const unsigned short* Ab = A + row0 * K;
  const unsigned short* Bb = Bm + col0 * K;
  // staging chunk mapping: chunk li = wave*64+lane (0..255) then 256+...
  // global src (per-lane): row = li>>2, 8-elem segment = li&3
  // LDS dest: linear, chunk li at element offset li*8 -> wave-uniform base + lane*16B
  const int li0 = tid, li1 = 256 + tid;
  const int rw0 = li0 >> 2, sg0 = (li0 & 3) * 8;
  const int rw1 = li1 >> 2, sg1 = (li1 & 3) * 8;
  unsigned short* As0 = As + wave * 512;
  unsigned short* Bs0 = Bs + wave * 512;
  unsigned short* As1 = As + 2048 + wave * 512;
  unsigned short* Bs1 = Bs + 2048 + wave * 512;
  const unsigned short* Ap0 = Ab + (size_t)rw0 * K + sg0;
  const unsigned short* Bp0 = Bb + (size_t)rw0 * K + sg0;
  const unsigned short* Ap1 = Ab + (size_t)rw1 * K + sg1;
  const unsigned short* Bp1 = Bb + (size_t)rw1 * K + sg1;

  f32x4 acc[4][4];
#pragma unroll
  for (int i = 0; i < 4; ++i)
#pragma unroll
    for (int j = 0; j < 4; ++j) acc[i][j] = (f32x4){0.f, 0.f, 0.f, 0.f};

  for (int k0 = 0; k0 < K; k0 += 32) {
    __syncthreads();                  // all waves done reading LDS from prev iter
    glds16(Ap0 + k0, As0);
    glds16(Bp0 + k0, Bs0);
    glds16(Ap1 + k0, As1);
    glds16(Bp1 + k0, Bs1);
    __syncthreads();                  // vmcnt(0) drain -> staged tile visible
    short8 aF[4], bF[4];
#pragma unroll
    for (int i = 0; i < 4; ++i) aF[i] = *(const short8*)(As + (wm + i * 16 + r) * 32 + quad * 8);
#pragma unroll
    for (int j = 0; j < 4; ++j) bF[j] = *(const short8*)(Bs + (wn + j * 16 + r) * 32 + quad * 8);
#pragma unroll
    for (int i = 0; i < 4; ++i)
#pragma unroll
      for (int j = 0; j < 4; ++j)
        acc[i][j] = __builtin_amdgcn_mfma_f32_16x16x32_bf16(aF[i], bF[j], acc[i][j], 0, 0, 0);
  }
  // epilogue: C/D layout col=lane&15, row=quad*4+reg
  unsigned short* Cb = (unsigned short*)Cout;
  float* Cf = (float*)Cout;
#pragma unroll
  for (int j = 0; j < 4; ++j) {
    const size_t gcol = col0 + wn + j * 16 + r;
    float bv = 0.f;
    if (EPI == 2 || EPI == 3) bv = bias[gcol];
#pragma unroll
    for (int i = 0; i < 4; ++i) {
      const size_t grow = row0 + wm + i * 16 + quad * 4;
#pragma unroll
      for (int tt = 0; tt < 4; ++tt) {
        float v = acc[i][j][tt] + bv;
        size_t idx = (grow + tt) * (size_t)N + gcol;
        if (EPI == 2) {
          v = 0.5f * v * (1.0f + erff(v * 0.70710678118654752f));
          Cb[idx] = f2bf(v);
        } else if (EPI == 0) {
          Cb[idx] = f2bf(v);
        } else if (EPI == 3) {
          Cf[idx] = v;
        } else {
          Cf[idx] += v;
        }
      }
    }
  }
}

// ---------------- chunked scan over S (32 chunks x 64 steps), in-place -----
__global__ void scan_carry_k(const unsigned short* __restrict__ Bu, const float* __restrict__ lamP,
                             float* __restrict__ carry, int l) {
  int t = blockIdx.x * 256 + threadIdx.x;    // 131072 = B*32*1024
  int u = t & 1023, c = (t >> 10) & 31, b = t >> 15;
  float lr = lamP[l * 1024 + u], li = lamP[4096 + l * 1024 + u];
  const unsigned short* base = Bu + ((size_t)(b * 2048 + c * 64)) * 2048 + u;
  float sr = 0.f, si = 0.f;
  for (int g = 0; g < 4; ++g) {
#pragma unroll
    for (int j = 0; j < 16; ++j) {
      size_t off = (size_t)(g * 16 + j) * 2048;
      float vr = bf2f(base[off]), vi = bf2f(base[off + 1024]);
      float nr = lr * sr - li * si + vr;
      si = lr * si + li * sr + vi;
      sr = nr;
    }
  }
  size_t idx = ((size_t)b * 32 + c) * 1024 + u;
  carry[idx] = sr; carry[131072 + idx] = si;
}

__global__ void scan_comb_k(const float* __restrict__ carry, const float* __restrict__ lamP,
                            float* __restrict__ inst, int l) {
  int t = blockIdx.x * 256 + threadIdx.x;  // 4096
  int u = t & 1023, b = t >> 10;
  float tr = lamP[3 * 4096 + l * 1024 + u], ti = lamP[4 * 4096 + l * 1024 + u];
  float pr = 0.f, pi = 0.f;
  for (int c = 0; c < 32; ++c) {
    size_t idx = ((size_t)b * 32 + c) * 1024 + u;
    inst[idx] = pr; inst[131072 + idx] = pi;
    float cr = carry[idx], ci = carry[131072 + idx];
    float nr = tr * pr - ti * pi + cr;
    pi = tr * pi + ti * pr + ci;
    pr = nr;
  }
}

__global__ void scan_final_k(unsigned short* __restrict__ Bu, const float* __restrict__ lamP,
                             const float* __restrict__ inst, int l) {
  int t = blockIdx.x * 256 + threadIdx.x;
  int u = t & 1023, c = (t >> 10) & 31, b = t >> 15;
  float lr = lamP[l * 1024 + u], li = lamP[4096 + l * 1024 + u];
  size_t idx = ((size_t)b * 32 + c) * 1024 + u;
  float sr = inst[idx], si = inst[131072 + idx];
  unsigned short* base = Bu + ((size_t)(b * 2048 + c * 64)) * 2048 + u;
  for (int g = 0; g < 4; ++g) {
#pragma unroll
    for (int j = 0; j < 16; ++j) {
      size_t off = (size_t)(g * 16 + j) * 2048;
      float vr = bf2f(base[off]), vi = bf2f(base[off + 1024]);
      float nr = lr * sr - li * si + vr;
      si = lr * si + li * sr + vi;
      sr = nr;
      base[off] = f2bf(sr); base[off + 1024] = f2bf(si);
    }
  }
}

// ---------------- fused residual + (optional D*h) + RMS-LN + bias ----------
// h: bf16. y: bf16 (YF32=0) or fp32 (YF32=1). Dv/bias: fp32.
// out: bf16 (OUTF32=0) or fp32 (OUTF32=1).
template <int HASD, int YF32, int OUTF32>
__global__ void ln_k(const unsigned short* __restrict__ h, const void* __restrict__ yv,
                     const float* __restrict__ Dv, const float* __restrict__ bias,
                     void* __restrict__ outv) {
  int wave = threadIdx.x >> 6, lane = threadIdx.x & 63;
  size_t row = (size_t)blockIdx.x * 4 + wave;
  const unsigned short* hr = h + row * 1024;
  float x[16]; float ss = 0.f;
#pragma unroll
  for (int cc = 0; cc < 2; ++cc) {
    int col = cc * 512 + lane * 8;
    uint4 hv = *(const uint4*)(hr + col);
    const unsigned short* hp = (const unsigned short*)&hv;
    float yf[8];
    if (YF32) {
      const float* yr = (const float*)yv + row * 1024 + col;
      float4 y0 = *(const float4*)yr, y1 = *(const float4*)(yr + 4);
      yf[0] = y0.x; yf[1] = y0.y; yf[2] = y0.z; yf[3] = y0.w;
      yf[4] = y1.x; yf[5] = y1.y; yf[6] = y1.z; yf[7] = y1.w;
    } else {
      uint4 yv4 = *(const uint4*)((const unsigned short*)yv + row * 1024 + col);
      const unsigned short* yp = (const unsigned short*)&yv4;
#pragma unroll
      for (int j = 0; j < 8; ++j) yf[j] = bf2f(yp[j]);
    }
    if (HASD) {
      const float* dp = Dv + col;
      float4 d0 = *(const float4*)dp, d1 = *(const float4*)(dp + 4);
      float df[8] = {d0.x, d0.y, d0.z, d0.w, d1.x, d1.y, d1.z, d1.w};
#pragma unroll
      for (int j = 0; j < 8; ++j) {
        float hf = bf2f(hp[j]);
        float v = hf + yf[j] + df[j] * hf;
        x[cc * 8 + j] = v; ss += v * v;
      }
    } else {
#pragma unroll
      for (int j = 0; j < 8; ++j) {
        float v = bf2f(hp[j]) + yf[j];
        x[cc * 8 + j] = v; ss += v * v;
      }
    }
  }
#pragma unroll
  for (int off = 32; off > 0; off >>= 1) ss += __shfl_xor(ss, off);
  float rs = rsqrtf(ss * (1.0f / 1024.0f) + 1e-12f);
#pragma unroll
  for (int cc = 0; cc < 2; ++cc) {
    int col = cc * 512 + lane * 8;
    const float* bp = bias + col;
    float4 b0 = *(const float4*)bp, b1 = *(const float4*)(bp + 4);
    float bf[8] = {b0.x, b0.y, b0.z, b0.w, b1.x, b1.y, b1.z, b1.w};
    if (OUTF32) {
      float* op = (float*)outv + row * 1024 + col;
      float4 o0, o1;
      o0.x = x[cc*8+0]*rs + bf[0]; o0.y = x[cc*8+1]*rs + bf[1];
      o0.z = x[cc*8+2]*rs + bf[2]; o0.w = x[cc*8+3]*rs + bf[3];
      o1.x = x[cc*8+4]*rs + bf[4]; o1.y = x[cc*8+5]*rs + bf[5];
      o1.z = x[cc*8+6]*rs + bf[6]; o1.w = x[cc*8+7]*rs + bf[7];
      *(float4*)op = o0; *(float4*)(op + 4) = o1;
    } else {
      uint4 o; unsigned short* op = (unsigned short*)&o;
#pragma unroll
      for (int j = 0; j < 8; ++j) op[j] = f2bf(x[cc * 8 + j] * rs + bf[j]);
      *(uint4*)((unsigned short*)outv + row * 1024 + col) = o;
    }
  }
}

// ---------------------------------------------------------------------------
extern "C" void kernel_launch(void* const* d_in, const int* in_sizes, int n_in,
                              void* d_out, int out_size, void* d_ws, size_t ws_size,
                              hipStream_t stream) {
  const int H = 1024, F = 4096;
  const int*   ids = (const int*)d_in[0];
  const float* we  = (const float*)d_in[1];
  const float* pe  = (const float*)d_in[2];
  const float* nu  = (const float*)d_in[3];
  const float* th  = (const float*)d_in[4];
  const float* Bre = (const float*)d_in[5];
  const float* Bim = (const float*)d_in[6];
  const float* Cre = (const float*)d_in[7];
  const float* Cim = (const float*)d_in[8];
  const float* Dv  = (const float*)d_in[9];
  const float* rnb = (const float*)d_in[10];
  const float* w1  = (const float*)d_in[11];
  const float* b1  = (const float*)d_in[12];
  const float* w2  = (const float*)d_in[13];
  const float* b2  = (const float*)d_in[14];
  const float* fnb = (const float*)d_in[15];
  float* out = (float*)d_out;

  // Workspace (~78 MB). facc aliases Bu (disjoint lifetimes); t1 chunk aliases y.
  char* w = (char*)d_ws;
  float* lamP  = (float*)w; w += (size_t)5 * 4096 * 4;                      // 80KB
  float* carry = (float*)w; w += (size_t)2 * 131072 * 4;                    // 1MB
  float* inst  = (float*)w; w += (size_t)2 * 131072 * 4;                    // 1MB
  unsigned short* Bw   = (unsigned short*)w; w += (size_t)2048 * 1024 * 2;  // 4MB
  unsigned short* Cw   = (unsigned short*)w; w += (size_t)1024 * 2048 * 2;  // 4MB
  unsigned short* w1c  = (unsigned short*)w; w += (size_t)1024 * 1024 * 2;  // 2MB
  unsigned short* w2c  = (unsigned short*)w; w += (size_t)1024 * 1024 * 2;  // 2MB
  unsigned short* hcur = (unsigned short*)w; w += (size_t)8192 * 1024 * 2;  // 16MB
  unsigned short* Bu   = (unsigned short*)w;                                // 32MB (shared)
  float*          facc = (float*)Bu;                                        //   (alias)
  w += (size_t)8192 * 2048 * 2;
  unsigned short* ybt  = (unsigned short*)w; w += (size_t)8192 * 1024 * 2;  // 16MB (y / t1 chunk)

  embed_k<<<4096, 256, 0, stream>>>(ids, we, pe, hcur);
  prep_lam_k<<<16, 256, 0, stream>>>(nu, th, lamP);

  for (int l = 0; l < 4; ++l) {
    prep_w_k<<<2048, 256, 0, stream>>>(Bre + (size_t)l * H * H, Bim + (size_t)l * H * H,
                                       Cre + (size_t)l * H * H, Cim + (size_t)l * H * H,
                                       lamP + 2 * 4096 + l * 1024, Bw, Cw);
    // Bu(re||im) = hcur @ Bw^T          [8192,2048]
    gemm_nt<0><<<dim3(64, 16), 256, 0, stream>>>(hcur, Bw, Bu, nullptr, 8192, 2048, 1024);
    // in-place associative scan over S
    scan_carry_k<<<512, 256, 0, stream>>>(Bu, lamP, carry, l);
    scan_comb_k<<<16, 256, 0, stream>>>(carry, lamP, inst, l);
    scan_final_k<<<512, 256, 0, stream>>>(Bu, lamP, inst, l);
    // y = states @ Cw^T                  [8192,1024] -> ybt (bf16)
    gemm_nt<0><<<dim3(64, 8), 256, 0, stream>>>(Bu, Cw, ybt, nullptr, 8192, 1024, 2048);
    // h = LN(h + y + D*h) + rnn bias     (Bu dead from here; facc takes over)
    ln_k<1, 0, 0><<<2048, 256, 0, stream>>>(hcur, ybt, Dv + l * H, rnb + l * H, hcur);
    // FFN chunked over F (4 x 1024): facc = sum_c gelu(h@w1c^T+b1c) @ w2c^T (+b2)
    for (int c = 0; c < 4; ++c) {
      prep_ffn_k<<<1024, 256, 0, stream>>>(w1 + (size_t)l * F * H, w2 + (size_t)l * H * F,
                                           w1c, w2c, c);
      gemm_nt<2><<<dim3(64, 8), 256, 0, stream>>>(hcur, w1c, ybt,
                                                  b1 + (size_t)l * F + c * 1024, 8192, 1024, 1024);
      if (c == 0)
        gemm_nt<3><<<dim3(64, 8), 256, 0, stream>>>(ybt, w2c, facc, b2 + (size_t)l * H,
                                                    8192, 1024, 1024);
      else
        gemm_nt<4><<<dim3(64, 8), 256, 0, stream>>>(ybt, w2c, facc, nullptr,
                                                    8192, 1024, 1024);
    }
    // h = LN(h + ffn) + ffn bias  (last layer -> fp32 d_out)
    if (l == 3)
      ln_k<0, 1, 1><<<2048, 256, 0, stream>>>(hcur, facc, nullptr, fnb + l * H, out);
    else
      ln_k<0, 1, 0><<<2048, 256, 0, stream>>>(hcur, facc, nullptr, fnb + l * H, hcur);
  }
}

// Round 2
// 1666.529 us; speedup vs baseline: 1.2187x; 1.2027x over previous
//
#include <hip/hip_runtime.h>
#include <hip/hip_bf16.h>
#include <math.h>

typedef __attribute__((ext_vector_type(8))) short short8;
typedef __attribute__((ext_vector_type(4))) float f32x4;

__device__ __forceinline__ float bf2f(unsigned short u) {
  union { unsigned int i; float f; } v; v.i = ((unsigned int)u) << 16; return v.f;
}
__device__ __forceinline__ unsigned short f2bf(float f) {
  union { float f; unsigned int i; } v; v.f = f;
  unsigned int r = v.i + 0x7fffu + ((v.i >> 16) & 1u);
  return (unsigned short)(r >> 16);
}
// convert 8 consecutive fp32 (two aligned float4) -> 8 bf16 (uint4)
__device__ __forceinline__ uint4 cvt8(const float* __restrict__ src, float scale) {
  float4 a = *(const float4*)src;
  float4 b = *(const float4*)(src + 4);
  uint4 o; unsigned short* op = (unsigned short*)&o;
  op[0] = f2bf(a.x * scale); op[1] = f2bf(a.y * scale);
  op[2] = f2bf(a.z * scale); op[3] = f2bf(a.w * scale);
  op[4] = f2bf(b.x * scale); op[5] = f2bf(b.y * scale);
  op[6] = f2bf(b.z * scale); op[7] = f2bf(b.w * scale);
  return o;
}
// async global->LDS, 16 bytes per lane. LDS dest = wave-uniform base + lane*16.
__device__ __forceinline__ void glds16(const unsigned short* g, unsigned short* s) {
  __builtin_amdgcn_global_load_lds(
      (const __attribute__((address_space(1))) unsigned int*)g,
      (__attribute__((address_space(3))) unsigned int*)s, 16, 0, 0);
}

// ---------------- embedding: h = bf16(word_emb[ids] + pos_emb[s]) ----------
__global__ void embed_k(const int* __restrict__ ids, const float* __restrict__ we,
                        const float* __restrict__ pe, unsigned short* __restrict__ h) {
  int t = blockIdx.x * 256 + threadIdx.x;           // 1M threads, 8 elems each
  int c8 = (t & 127) * 8, row = t >> 7;
  int s = row & 2047;
  int id = ids[row];
  const float* ap = we + (size_t)id * 1024 + c8;
  const float* bp = pe + (size_t)s * 1024 + c8;
  float4 a0 = *(const float4*)ap, a1 = *(const float4*)(ap + 4);
  float4 b0 = *(const float4*)bp, b1 = *(const float4*)(bp + 4);
  uint4 o; unsigned short* op = (unsigned short*)&o;
  op[0] = f2bf(a0.x + b0.x); op[1] = f2bf(a0.y + b0.y);
  op[2] = f2bf(a0.z + b0.z); op[3] = f2bf(a0.w + b0.w);
  op[4] = f2bf(a1.x + b1.x); op[5] = f2bf(a1.y + b1.y);
  op[6] = f2bf(a1.z + b1.z); op[7] = f2bf(a1.w + b1.w);
  *(uint4*)(h + (size_t)row * 1024 + c8) = o;
}

// ---------------- lambda / gamma / lambda^64 precompute (all layers) -------
__global__ void prep_lam_k(const float* __restrict__ nu_log,
                           const float* __restrict__ theta_log,
                           float* __restrict__ lamP) {
  int t = blockIdx.x * 256 + threadIdx.x;  // 4096 = L*H
  float nu = nu_log[t], th = theta_log[t];
  float mag = expf(-expf(nu));
  float eth = expf(th);
  float lr = mag * cosf(eth), li = mag * sinf(eth);
  float g2 = 1.0f - mag * mag; if (g2 < 0.f) g2 = 0.f;
  float pr = 1.f, pi = 0.f;
#pragma unroll 1
  for (int i = 0; i < 64; ++i) { float nr = pr * lr - pi * li; pi = pr * li + pi * lr; pr = nr; }
  lamP[t] = lr;                     // plane 0: lam_re
  lamP[4096 + t] = li;              // plane 1: lam_im
  lamP[2 * 4096 + t] = sqrtf(g2);   // plane 2: gamma
  lamP[3 * 4096 + t] = pr;          // plane 3: lam^64 re
  lamP[4 * 4096 + t] = pi;          // plane 4: lam^64 im
}

// -------- per-layer weight repack (fp32->bf16): Bw=[B_re*g;B_im*g], Cw=[C_re|-C_im]
__global__ void prep_w_k(const float* __restrict__ Bre, const float* __restrict__ Bim,
                         const float* __restrict__ Cre, const float* __restrict__ Cim,
                         const float* __restrict__ gamma, unsigned short* __restrict__ Bw,
                         unsigned short* __restrict__ Cw) {
  int t = blockIdx.x * 256 + threadIdx.x;  // 524288
  if (t < 262144) {
    int n = t >> 7, h8 = (t & 127) * 8;
    int u = n & 1023;
    const float* src = (n < 1024 ? Bre : Bim) + (size_t)u * 1024 + h8;
    *(uint4*)(Bw + (size_t)n * 1024 + h8) = cvt8(src, gamma[u]);
  } else {
    int t2 = t - 262144;
    int hrow = t2 >> 8, u8 = (t2 & 255) * 8;
    uint4 o;
    if (u8 < 1024) o = cvt8(Cre + (size_t)hrow * 1024 + u8, 1.0f);
    else           o = cvt8(Cim + (size_t)hrow * 1024 + (u8 - 1024), -1.0f);
    *(uint4*)(Cw + (size_t)hrow * 2048 + u8) = o;
  }
}

// -------- FFN weight convert (whole layer): w1b[4096,1024], w2b[1024,4096] --
__global__ void prep_ffn_k(const float* __restrict__ w1l, const float* __restrict__ w2l,
                           unsigned short* __restrict__ w1b, unsigned short* __restrict__ w2b) {
  int t = blockIdx.x * 256 + threadIdx.x;  // 1048576 threads, 8 elems each
  size_t off = (size_t)t * 8;
  if (t < 524288) {
    *(uint4*)(w1b + off) = cvt8(w1l + off, 1.0f);
  } else {
    size_t o2 = off - 4194304;
    *(uint4*)(w2b + o2) = cvt8(w2l + o2, 1.0f);
  }
}

// ---------------- NT bf16 GEMM: C = A[M,K] * B[N,K]^T ----------------------
// 2-phase double-buffered: stage tile t+1 (global_load_lds w=16) BEFORE
// ds_read+MFMA of tile t; single barrier per K-step (its vmcnt(0)/lgkmcnt(0)
// drain makes the prefetched tile visible). 128x128 tile, BK=32.
// EPI: 0 = bf16 store; 2 = bf16 store, +bias +gelu(exact); 3 = fp32 store, +bias
template <int EPI>
__global__ __launch_bounds__(256, 2) void gemm_nt(
    const unsigned short* __restrict__ A, const unsigned short* __restrict__ Bm,
    void* __restrict__ Cout, const float* __restrict__ bias, int M, int N, int K) {
  __shared__ unsigned short As[2 * 128 * 32];
  __shared__ unsigned short Bs[2 * 128 * 32];
  const int tid = threadIdx.x;
  const int lane = tid & 63;
  const int wave = tid >> 6;
  const int quad = lane >> 4, r = lane & 15;
  const int wm = (wave >> 1) * 64, wn = (wave & 1) * 64;
  const size_t row0 = (size_t)blockIdx.x * 128;
  const size_t col0 = (size_t)blockIdx.y * 128;
  const unsigned short* Ab = A + row0 * K;
  const unsigned short* Bb = Bm + col0 * K;
  // staging chunk mapping: chunk li (0..511) covers row li>>2, k-segment (li&3)*8.
  // LDS dest linear: chunk li at element offset li*8 (wave-uniform base + lane*16B).
  const int li0 = tid, li1 = 256 + tid;
  const int rw0 = li0 >> 2, sg0 = (li0 & 3) * 8;
  const int rw1 = li1 >> 2, sg1 = (li1 & 3) * 8;
  unsigned short* As0 = As + wave * 512;
  unsigned short* Bs0 = Bs + wave * 512;
  unsigned short* As1 = As + 2048 + wave * 512;
  unsigned short* Bs1 = Bs + 2048 + wave * 512;
  const unsigned short* Ap0 = Ab + (size_t)rw0 * K + sg0;
  const unsigned short* Bp0 = Bb + (size_t)rw0 * K + sg0;
  const unsigned short* Ap1 = Ab + (size_t)rw1 * K + sg1;
  const unsigned short* Bp1 = Bb + (size_t)rw1 * K + sg1;

  f32x4 acc[4][4];
#pragma unroll
  for (int i = 0; i < 4; ++i)
#pragma unroll
    for (int j = 0; j < 4; ++j) acc[i][j] = (f32x4){0.f, 0.f, 0.f, 0.f};

  // prologue: stage tile 0 into buffer 0
  glds16(Ap0, As0);
  glds16(Bp0, Bs0);
  glds16(Ap1, As1);
  glds16(Bp1, Bs1);
  __syncthreads();

  const int nk = K >> 5;
  int cur = 0;
  for (int t = 0; t < nk; ++t) {
    if (t + 1 < nk) {                 // issue next-tile loads FIRST (overlap MFMA)
      const int kn = (t + 1) << 5;
      const int nb = (cur ^ 1) * 4096;
      glds16(Ap0 + kn, As0 + nb);
      glds16(Bp0 + kn, Bs0 + nb);
      glds16(Ap1 + kn, As1 + nb);
      glds16(Bp1 + kn, Bs1 + nb);
    }
    const unsigned short* Ac = As + cur * 4096;
    const unsigned short* Bc = Bs + cur * 4096;
    short8 aF[4], bF[4];
#pragma unroll
    for (int i = 0; i < 4; ++i) aF[i] = *(const short8*)(Ac + (wm + i * 16 + r) * 32 + quad * 8);
#pragma unroll
    for (int j = 0; j < 4; ++j) bF[j] = *(const short8*)(Bc + (wn + j * 16 + r) * 32 + quad * 8);
#pragma unroll
    for (int i = 0; i < 4; ++i)
#pragma unroll
      for (int j = 0; j < 4; ++j)
        acc[i][j] = __builtin_amdgcn_mfma_f32_16x16x32_bf16(aF[i], bF[j], acc[i][j], 0, 0, 0);
    __syncthreads();                  // drains vmcnt(0): prefetched tile now visible
    cur ^= 1;
  }
  // epilogue: C/D layout col=lane&15, row=quad*4+reg
  unsigned short* Cb = (unsigned short*)Cout;
  float* Cf = (float*)Cout;
#pragma unroll
  for (int j = 0; j < 4; ++j) {
    const size_t gcol = col0 + wn + j * 16 + r;
    float bv = 0.f;
    if (EPI == 2 || EPI == 3) bv = bias[gcol];
#pragma unroll
    for (int i = 0; i < 4; ++i) {
      const size_t grow = row0 + wm + i * 16 + quad * 4;
#pragma unroll
      for (int tt = 0; tt < 4; ++tt) {
        float v = acc[i][j][tt] + bv;
        size_t idx = (grow + tt) * (size_t)N + gcol;
        if (EPI == 2) {
          v = 0.5f * v * (1.0f + erff(v * 0.70710678118654752f));
          Cb[idx] = f2bf(v);
        } else if (EPI == 0) {
          Cb[idx] = f2bf(v);
        } else {
          Cf[idx] = v;
        }
      }
    }
  }
}

// ---------------- chunked scan over S (32 chunks x 64 steps), in-place -----
__global__ void scan_carry_k(const unsigned short* __restrict__ Bu, const float* __restrict__ lamP,
                             float* __restrict__ carry, int l) {
  int t = blockIdx.x * 256 + threadIdx.x;    // 131072 = B*32*1024
  int u = t & 1023, c = (t >> 10) & 31, b = t >> 15;
  float lr = lamP[l * 1024 + u], li = lamP[4096 + l * 1024 + u];
  const unsigned short* base = Bu + ((size_t)(b * 2048 + c * 64)) * 2048 + u;
  float sr = 0.f, si = 0.f;
  for (int g = 0; g < 4; ++g) {
#pragma unroll
    for (int j = 0; j < 16; ++j) {
      size_t off = (size_t)(g * 16 + j) * 2048;
      float vr = bf2f(base[off]), vi = bf2f(base[off + 1024]);
      float nr = lr * sr - li * si + vr;
      si = lr * si + li * sr + vi;
      sr = nr;
    }
  }
  size_t idx = ((size_t)b * 32 + c) * 1024 + u;
  carry[idx] = sr; carry[131072 + idx] = si;
}

__global__ void scan_comb_k(const float* __restrict__ carry, const float* __restrict__ lamP,
                            float* __restrict__ inst, int l) {
  int t = blockIdx.x * 256 + threadIdx.x;  // 4096
  int u = t & 1023, b = t >> 10;
  float tr = lamP[3 * 4096 + l * 1024 + u], ti = lamP[4 * 4096 + l * 1024 + u];
  float pr = 0.f, pi = 0.f;
  for (int c = 0; c < 32; ++c) {
    size_t idx = ((size_t)b * 32 + c) * 1024 + u;
    inst[idx] = pr; inst[131072 + idx] = pi;
    float cr = carry[idx], ci = carry[131072 + idx];
    float nr = tr * pr - ti * pi + cr;
    pi = tr * pi + ti * pr + ci;
    pr = nr;
  }
}

__global__ void scan_final_k(unsigned short* __restrict__ Bu, const float* __restrict__ lamP,
                             const float* __restrict__ inst, int l) {
  int t = blockIdx.x * 256 + threadIdx.x;
  int u = t & 1023, c = (t >> 10) & 31, b = t >> 15;
  float lr = lamP[l * 1024 + u], li = lamP[4096 + l * 1024 + u];
  size_t idx = ((size_t)b * 32 + c) * 1024 + u;
  float sr = inst[idx], si = inst[131072 + idx];
  unsigned short* base = Bu + ((size_t)(b * 2048 + c * 64)) * 2048 + u;
  for (int g = 0; g < 4; ++g) {
#pragma unroll
    for (int j = 0; j < 16; ++j) {
      size_t off = (size_t)(g * 16 + j) * 2048;
      float vr = bf2f(base[off]), vi = bf2f(base[off + 1024]);
      float nr = lr * sr - li * si + vr;
      si = lr * si + li * sr + vi;
      sr = nr;
      base[off] = f2bf(sr); base[off + 1024] = f2bf(si);
    }
  }
}

// ---------------- fused residual + (optional D*h) + RMS-LN + bias ----------
// h: bf16. y: bf16 (YF32=0) or fp32 (YF32=1). Dv/bias: fp32.
// out: bf16 (OUTF32=0) or fp32 (OUTF32=1).
template <int HASD, int YF32, int OUTF32>
__global__ void ln_k(const unsigned short* __restrict__ h, const void* __restrict__ yv,
                     const float* __restrict__ Dv, const float* __restrict__ bias,
                     void* __restrict__ outv) {
  int wave = threadIdx.x >> 6, lane = threadIdx.x & 63;
  size_t row = (size_t)blockIdx.x * 4 + wave;
  const unsigned short* hr = h + row * 1024;
  float x[16]; float ss = 0.f;
#pragma unroll
  for (int cc = 0; cc < 2; ++cc) {
    int col = cc * 512 + lane * 8;
    uint4 hv = *(const uint4*)(hr + col);
    const unsigned short* hp = (const unsigned short*)&hv;
    float yf[8];
    if (YF32) {
      const float* yr = (const float*)yv + row * 1024 + col;
      float4 y0 = *(const float4*)yr, y1 = *(const float4*)(yr + 4);
      yf[0] = y0.x; yf[1] = y0.y; yf[2] = y0.z; yf[3] = y0.w;
      yf[4] = y1.x; yf[5] = y1.y; yf[6] = y1.z; yf[7] = y1.w;
    } else {
      uint4 yv4 = *(const uint4*)((const unsigned short*)yv + row * 1024 + col);
      const unsigned short* yp = (const unsigned short*)&yv4;
#pragma unroll
      for (int j = 0; j < 8; ++j) yf[j] = bf2f(yp[j]);
    }
    if (HASD) {
      const float* dp = Dv + col;
      float4 d0 = *(const float4*)dp, d1 = *(const float4*)(dp + 4);
      float df[8] = {d0.x, d0.y, d0.z, d0.w, d1.x, d1.y, d1.z, d1.w};
#pragma unroll
      for (int j = 0; j < 8; ++j) {
        float hf = bf2f(hp[j]);
        float v = hf + yf[j] + df[j] * hf;
        x[cc * 8 + j] = v; ss += v * v;
      }
    } else {
#pragma unroll
      for (int j = 0; j < 8; ++j) {
        float v = bf2f(hp[j]) + yf[j];
        x[cc * 8 + j] = v; ss += v * v;
      }
    }
  }
#pragma unroll
  for (int off = 32; off > 0; off >>= 1) ss += __shfl_xor(ss, off);
  float rs = rsqrtf(ss * (1.0f / 1024.0f) + 1e-12f);
#pragma unroll
  for (int cc = 0; cc < 2; ++cc) {
    int col = cc * 512 + lane * 8;
    const float* bp = bias + col;
    float4 b0 = *(const float4*)bp, b1 = *(const float4*)(bp + 4);
    float bf[8] = {b0.x, b0.y, b0.z, b0.w, b1.x, b1.y, b1.z, b1.w};
    if (OUTF32) {
      float* op = (float*)outv + row * 1024 + col;
      float4 o0, o1;
      o0.x = x[cc*8+0]*rs + bf[0]; o0.y = x[cc*8+1]*rs + bf[1];
      o0.z = x[cc*8+2]*rs + bf[2]; o0.w = x[cc*8+3]*rs + bf[3];
      o1.x = x[cc*8+4]*rs + bf[4]; o1.y = x[cc*8+5]*rs + bf[5];
      o1.z = x[cc*8+6]*rs + bf[6]; o1.w = x[cc*8+7]*rs + bf[7];
      *(float4*)op = o0; *(float4*)(op + 4) = o1;
    } else {
      uint4 o; unsigned short* op = (unsigned short*)&o;
#pragma unroll
      for (int j = 0; j < 8; ++j) op[j] = f2bf(x[cc * 8 + j] * rs + bf[j]);
      *(uint4*)((unsigned short*)outv + row * 1024 + col) = o;
    }
  }
}

// ---------------------------------------------------------------------------
extern "C" void kernel_launch(void* const* d_in, const int* in_sizes, int n_in,
                              void* d_out, int out_size, void* d_ws, size_t ws_size,
                              hipStream_t stream) {
  const int H = 1024, F = 4096;
  const int*   ids = (const int*)d_in[0];
  const float* we  = (const float*)d_in[1];
  const float* pe  = (const float*)d_in[2];
  const float* nu  = (const float*)d_in[3];
  const float* th  = (const float*)d_in[4];
  const float* Bre = (const float*)d_in[5];
  const float* Bim = (const float*)d_in[6];
  const float* Cre = (const float*)d_in[7];
  const float* Cim = (const float*)d_in[8];
  const float* Dv  = (const float*)d_in[9];
  const float* rnb = (const float*)d_in[10];
  const float* w1  = (const float*)d_in[11];
  const float* b1  = (const float*)d_in[12];
  const float* w2  = (const float*)d_in[13];
  const float* b2  = (const float*)d_in[14];
  const float* fnb = (const float*)d_in[15];
  float* out = (float*)d_out;

  // Workspace (~174 MB of 512). facc (fp32, 32MB) aliases Bu (disjoint lifetimes).
  char* w = (char*)d_ws;
  float* lamP  = (float*)w; w += (size_t)5 * 4096 * 4;                      // 80KB
  float* carry = (float*)w; w += (size_t)2 * 131072 * 4;                    // 1MB
  float* inst  = (float*)w; w += (size_t)2 * 131072 * 4;                    // 1MB
  unsigned short* Bw   = (unsigned short*)w; w += (size_t)2048 * 1024 * 2;  // 4MB
  unsigned short* Cw   = (unsigned short*)w; w += (size_t)1024 * 2048 * 2;  // 4MB
  unsigned short* w1b  = (unsigned short*)w; w += (size_t)4096 * 1024 * 2;  // 8MB
  unsigned short* w2b  = (unsigned short*)w; w += (size_t)1024 * 4096 * 2;  // 8MB
  unsigned short* hcur = (unsigned short*)w; w += (size_t)8192 * 1024 * 2;  // 16MB
  unsigned short* Bu   = (unsigned short*)w;                                // 32MB (shared)
  float*          facc = (float*)Bu;                                        //   (alias)
  w += (size_t)8192 * 2048 * 2;
  unsigned short* ybt  = (unsigned short*)w; w += (size_t)8192 * 1024 * 2;  // 16MB
  unsigned short* t1   = (unsigned short*)w; w += (size_t)8192 * 4096 * 2;  // 64MB

  embed_k<<<4096, 256, 0, stream>>>(ids, we, pe, hcur);
  prep_lam_k<<<16, 256, 0, stream>>>(nu, th, lamP);

  for (int l = 0; l < 4; ++l) {
    prep_w_k<<<2048, 256, 0, stream>>>(Bre + (size_t)l * H * H, Bim + (size_t)l * H * H,
                                       Cre + (size_t)l * H * H, Cim + (size_t)l * H * H,
                                       lamP + 2 * 4096 + l * 1024, Bw, Cw);
    // Bu(re||im) = hcur @ Bw^T          [8192,2048]
    gemm_nt<0><<<dim3(64, 16), 256, 0, stream>>>(hcur, Bw, Bu, nullptr, 8192, 2048, 1024);
    // in-place associative scan over S
    scan_carry_k<<<512, 256, 0, stream>>>(Bu, lamP, carry, l);
    scan_comb_k<<<16, 256, 0, stream>>>(carry, lamP, inst, l);
    scan_final_k<<<512, 256, 0, stream>>>(Bu, lamP, inst, l);
    // y = states @ Cw^T                  [8192,1024] -> ybt (bf16)
    gemm_nt<0><<<dim3(64, 8), 256, 0, stream>>>(Bu, Cw, ybt, nullptr, 8192, 1024, 2048);
    // h = LN(h + y + D*h) + rnn bias
    ln_k<1, 0, 0><<<2048, 256, 0, stream>>>(hcur, ybt, Dv + l * H, rnb + l * H, hcur);
    // FFN (fused over full F=4096):
    prep_ffn_k<<<4096, 256, 0, stream>>>(w1 + (size_t)l * F * H, w2 + (size_t)l * H * F,
                                         w1b, w2b);
    // t1 = gelu(h @ w1^T + b1)           [8192,4096] bf16
    gemm_nt<2><<<dim3(64, 32), 256, 0, stream>>>(hcur, w1b, t1,
                                                 b1 + (size_t)l * F, 8192, 4096, 1024);
    // facc = t1 @ w2^T + b2              [8192,1024] fp32 (Bu dead; facc aliases it)
    gemm_nt<3><<<dim3(64, 8), 256, 0, stream>>>(t1, w2b, facc, b2 + (size_t)l * H,
                                                8192, 1024, 4096);
    // h = LN(h + ffn) + ffn bias  (last layer -> fp32 d_out)
    if (l == 3)
      ln_k<0, 1, 1><<<2048, 256, 0, stream>>>(hcur, facc, nullptr, fnb + l * H, out);
    else
      ln_k<0, 1, 0><<<2048, 256, 0, stream>>>(hcur, facc, nullptr, fnb + l * H, hcur);
  }
}